// Round 4
// baseline (103028.589 us; speedup 1.0000x reference)
//
#include <hip/hip_runtime.h>
#include <hip/hip_bf16.h>

#define T_STEPS 32768
#define DIM     1024    // D == U == 1024
#define NGATE   4096    // 4*U
#define GWG     128     // persistent workgroups in scan
#define UPW     8       // units per WG (1024/128)
#define NREP    8       // h-publish replicas (de-hotspot LLC lines)

typedef __attribute__((ext_vector_type(8))) short  short8;
typedef __attribute__((ext_vector_type(4))) float  floatx4;

static __device__ __forceinline__ unsigned short f2bf(float f) {
    union { __hip_bfloat16 h; unsigned short u; } cv;
    cv.h = __float2bfloat16(f);
    return cv.u;
}
static __device__ __forceinline__ float fast_sigmoid(float x) {
    float e = __builtin_amdgcn_exp2f(x * -1.442695041f);   // exp(-x)
    return __builtin_amdgcn_rcpf(1.f + e);
}
static __device__ __forceinline__ float fast_tanh(float x) {
    float e = __builtin_amdgcn_exp2f(x * -2.885390082f);   // exp(-2x)
    return __builtin_amdgcn_rcpf(1.f + e) * 2.f - 1.f;
}

// ---------------- conversion kernels ----------------

__global__ void conv_x_kernel(const float* __restrict__ x,
                              unsigned short* __restrict__ xb, long n4) {
    long i = (long)blockIdx.x * blockDim.x + threadIdx.x;
    if (i >= n4) return;
    floatx4 v = ((const floatx4*)x)[i];
    unsigned long long p =  (unsigned long long)f2bf(v[0])
                         | ((unsigned long long)f2bf(v[1]) << 16)
                         | ((unsigned long long)f2bf(v[2]) << 32)
                         | ((unsigned long long)f2bf(v[3]) << 48);
    ((unsigned long long*)xb)[i] = p;
}

// kernel fp32 [K=1024][4096] -> Wbt bf16 [N=4096][K=1024], gate/unit remap:
// n(c) = [wg][gate][unit_in_wg] so each scan WG reads 32 contiguous zx cols.
__global__ void conv_w_kernel(const float* __restrict__ kern,
                              unsigned short* __restrict__ wbt) {
    int idx = blockIdx.x * 256 + threadIdx.x;
    int kb  = idx >> 12;                         // k block of 4 (0..255)
    int c   = idx & 4095;                        // original column
    int n = ((c & 1023) >> 3) * 32 + (c >> 10) * 8 + (c & 7);
    unsigned long long p = 0;
#pragma unroll
    for (int i = 0; i < 4; ++i) {
        float f = kern[(size_t)(kb * 4 + i) * NGATE + c];
        p |= (unsigned long long)f2bf(f) << (16 * i);
    }
    ((unsigned long long*)(wbt + (size_t)n * DIM))[kb] = p;
}

// hbuf8: NREP replicas x 2 parity x 1024 (fp32 h, int32 tag) pairs.
// Buffer parity b=t&1 holds h_t with tag t. Init: parity0 tag -2, parity1 tag -1.
__global__ void init_kernel(long long* hbuf8, float* cst) {
    int t = threadIdx.x;
    for (int u = t; u < 1024; u += 256) {
#pragma unroll
        for (int r = 0; r < NREP; ++r) {
            hbuf8[(size_t)r * 2048 + u]        = ((long long)(-2)) << 32;
            hbuf8[(size_t)r * 2048 + 1024 + u] = ((long long)(-1)) << 32;
        }
        cst[u] = 0.f;
    }
}

// ---------------- zx GEMM: zxf[t][n'] = sum_k xb[t][k] * Wbt[n'][k] ----------------

__global__ __launch_bounds__(256) void gemm_kernel(
        const unsigned short* __restrict__ xb,
        const unsigned short* __restrict__ wbt,
        float* __restrict__ zxf, int t0) {
    __shared__ unsigned short As[64 * 40];
    __shared__ unsigned short Bs[64 * 40];
    const int tid = threadIdx.x;
    const int w = tid >> 6, l = tid & 63;
    const int mBase = t0 + blockIdx.x * 64;
    const int nBase = blockIdx.y * 64;
    const int r  = tid >> 2;
    const int kc = (tid & 3) * 8;
    const int lm = l & 15, kq = l >> 4;

    floatx4 acc[4];
#pragma unroll
    for (int i = 0; i < 4; ++i) acc[i] = (floatx4){0.f, 0.f, 0.f, 0.f};

    for (int kt = 0; kt < DIM; kt += 32) {
        *(uint4*)&As[r * 40 + kc] = *(const uint4*)&xb [(size_t)(mBase + r) * DIM + kt + kc];
        *(uint4*)&Bs[r * 40 + kc] = *(const uint4*)&wbt[(size_t)(nBase + r) * DIM + kt + kc];
        __syncthreads();
        short8 a = *(const short8*)&As[(w * 16 + lm) * 40 + kq * 8];
#pragma unroll
        for (int i = 0; i < 4; ++i) {
            short8 b = *(const short8*)&Bs[(i * 16 + lm) * 40 + kq * 8];
            acc[i] = __builtin_amdgcn_mfma_f32_16x16x32_bf16(a, b, acc[i], 0, 0, 0);
        }
        __syncthreads();
    }
    const int rowq = (l >> 4) * 4;
#pragma unroll
    for (int i = 0; i < 4; ++i)
#pragma unroll
        for (int j = 0; j < 4; ++j) {
            int m = mBase + w * 16 + rowq + j;
            zxf[(size_t)(m - t0) * NGATE + nBase + i * 16 + lm] = acc[i][j];
        }
}

// ---------------- persistent recurrent scan ----------------
// 128 WGs x 256 thr. Wave w owns units {wg*8+2w, wg*8+2w+1} END-TO-END (full k):
// lane = kslice(=lane>>3, 8 slices of 128 k) x gate(=(lane&7)>>1) x du(=lane&1).
// In-wave shfl_xor reduce over kslices -> no cross-wave partial pass, no post-MAC
// barrier; all 4 waves compute gates & publish in parallel. One pre-MAC barrier;
// LDS h parity-double-buffered. h published to NREP replicas to spread LLC lines.

__global__ __launch_bounds__(256, 1) void scan_kernel(
        const float* __restrict__ zxf,
        const float* __restrict__ rker,
        const float* __restrict__ bias,
        float* __restrict__ out,
        long long* hbuf8, float* cst, int t0, int t1) {
    const int wg     = blockIdx.x;
    const int tid    = threadIdx.x;
    const int wave   = tid >> 6, lane = tid & 63;
    const int kslice = lane >> 3;
    const int idx8   = lane & 7;
    const int g      = idx8 >> 1;
    const int du     = idx8 & 1;
    const int unit   = wg * UPW + 2 * wave + du;      // global unit this lane's col belongs to
    const int c      = g * 1024 + unit;               // original gate-matrix column
    const int zxcol  = wg * 32 + g * 8 + 2 * wave + du;
    const int rep    = wg >> 4;                       // replica this WG polls

    // LDS h: 2 parity x 8 kslices x (128 + 4 pad) floats. Pad puts the 8 distinct
    // b128 MAC addresses on distinct banks (unpadded stride-512B = 8-way conflict).
    __shared__ float lds_h[2][8 * 132];

    // recurrent weights: 128 fp32 in registers (k range = [kslice*128, +128))
    float wr[128];
#pragma unroll
    for (int j = 0; j < 128; ++j)
        wr[j] = rker[(size_t)(kslice * 128 + j) * NGATE + c];

    float bias_v = bias[c];
    float cstate = 0.f;
    if (lane < 2) cstate = cst[unit];

    // zx prefetch (one step ahead)
    float zx_next = zxf[(size_t)0 * NGATE + zxcol];

    const int stage_idx = (wave * 2 + (lane >> 5)) * 132 + (lane & 31) * 4;

    for (int t = t0; t < t1; ++t) {
        const int par  = t & 1;
        const int rpar = (t + 1) & 1;
        const int etag = t - 1;
        const float zxv = zx_next;

        // poll own 4 pairs (predicated: done lanes stop loading and pre-stage)
        const long long* hb = hbuf8 + (size_t)rep * 2048 + (size_t)rpar * 1024
                              + wave * 256 + lane * 4;
        bool done = false;
        do {
            if (!done) {
                long long q0 = __hip_atomic_load(hb + 0, __ATOMIC_RELAXED, __HIP_MEMORY_SCOPE_AGENT);
                long long q1 = __hip_atomic_load(hb + 1, __ATOMIC_RELAXED, __HIP_MEMORY_SCOPE_AGENT);
                long long q2 = __hip_atomic_load(hb + 2, __ATOMIC_RELAXED, __HIP_MEMORY_SCOPE_AGENT);
                long long q3 = __hip_atomic_load(hb + 3, __ATOMIC_RELAXED, __HIP_MEMORY_SCOPE_AGENT);
                if ((int)(q0 >> 32) == etag && (int)(q1 >> 32) == etag &&
                    (int)(q2 >> 32) == etag && (int)(q3 >> 32) == etag) {
                    floatx4 hv;
                    hv[0] = __int_as_float((int)q0);
                    hv[1] = __int_as_float((int)q1);
                    hv[2] = __int_as_float((int)q2);
                    hv[3] = __int_as_float((int)q3);
                    *(floatx4*)&lds_h[rpar][stage_idx] = hv;
                    done = true;
                }
            }
        } while (!__all(done));
        __syncthreads();

        // MAC: 128 FMAs over this lane's kslice; 4 accumulators
        float z0 = 0.f, z1 = 0.f, z2 = 0.f, z3 = 0.f;
        const float* hp = &lds_h[rpar][kslice * 132];
#pragma unroll
        for (int j = 0; j < 32; ++j) {
            floatx4 hv = *(const floatx4*)&hp[j * 4];
            z0 = fmaf(wr[4 * j + 0], hv[0], z0);
            z1 = fmaf(wr[4 * j + 1], hv[1], z1);
            z2 = fmaf(wr[4 * j + 2], hv[2], z2);
            z3 = fmaf(wr[4 * j + 3], hv[3], z3);
        }
        float z = (z0 + z1) + (z2 + z3);
        // reduce over 8 kslices (lanes xor 8/16/32)
        z += __shfl_xor(z, 8);
        z += __shfl_xor(z, 16);
        z += __shfl_xor(z, 32);
        z += bias_v + zxv;

        // gather the 4 gates for unit du (cols at lanes {du, 2+du, 4+du, 6+du})
        int dl = lane & 1;
        float gi = __shfl(z, dl);
        float gf = __shfl(z, 2 + dl);
        float gg = __shfl(z, 4 + dl);
        float go = __shfl(z, 6 + dl);
        if (lane < 2) {
            float ig = fast_sigmoid(gi);
            float fg = fast_sigmoid(gf);
            float gv = fast_tanh(gg);
            float og = fast_sigmoid(go);
            cstate = fg * cstate + ig * gv;
            float h = og * fast_tanh(cstate);
            // publish (h, tag) to all replicas first (fire-and-forget, self-releasing)
            int2 pr;
            pr.x = __float_as_int(h);
            pr.y = t;
            long long* dst = hbuf8 + (size_t)par * 1024 + unit;
#pragma unroll
            for (int r = 0; r < NREP; ++r)
                asm volatile("global_store_dwordx2 %0, %1, off sc0 sc1"
                             :: "v"(dst + (size_t)r * 2048), "v"(pr) : "memory");
            out[(size_t)t * DIM + unit] = h;
        }
        // prefetch next step's zx
        int tn = (t + 1 < t1) ? (t + 1) : t;
        zx_next = zxf[(size_t)(tn - t0) * NGATE + zxcol];
    }
    if (lane < 2) cst[unit] = cstate;
}

// ---------------- host ----------------

extern "C" void kernel_launch(void* const* d_in, const int* in_sizes, int n_in,
                              void* d_out, int out_size, void* d_ws, size_t ws_size,
                              hipStream_t stream) {
    const float* x    = (const float*)d_in[0];   // [1,T,D]
    const float* kern = (const float*)d_in[1];   // [D,4U]
    const float* rker = (const float*)d_in[2];   // [U,4U]
    const float* bias = (const float*)d_in[3];   // [4U]
    float* out = (float*)d_out;                  // [1,T,U]

    char* ws = (char*)d_ws;
    size_t off = 0;
    auto alloc = [&](size_t bytes) {
        char* p = ws + off;
        off = (off + bytes + 255) & ~(size_t)255;
        return p;
    };
    unsigned short* wbt = (unsigned short*)alloc((size_t)NGATE * DIM * 2);   // 8 MB
    unsigned short* xb  = (unsigned short*)alloc((size_t)T_STEPS * DIM * 2); // 64 MB
    long long* hbuf8 = (long long*)alloc((size_t)NREP * 2048 * 8);           // 128 KB
    float*     cst   = (float*)alloc(1024 * 4);

    size_t avail = ws_size > off ? ws_size - off : 0;
    size_t tcmax = avail / ((size_t)NGATE * 4);
    if (tcmax > T_STEPS) tcmax = T_STEPS;
    int TC = (int)(tcmax & ~(size_t)63);
    if (TC < 64) TC = 64;
    float* zxf = (float*)alloc((size_t)TC * NGATE * 4);

    hipLaunchKernelGGL(conv_w_kernel, dim3(4096), dim3(256), 0, stream, kern, wbt);
    hipLaunchKernelGGL(conv_x_kernel, dim3((T_STEPS * DIM / 4 + 255) / 256), dim3(256),
                       0, stream, x, xb, (long)(T_STEPS * DIM / 4));
    hipLaunchKernelGGL(init_kernel, dim3(1), dim3(256), 0, stream, hbuf8, cst);

    for (int t0 = 0; t0 < T_STEPS; t0 += TC) {
        int tc = (T_STEPS - t0 < TC) ? (T_STEPS - t0) : TC;
        hipLaunchKernelGGL(gemm_kernel, dim3(tc / 64, NGATE / 64), dim3(256),
                           0, stream, xb, wbt, zxf, t0);
        hipLaunchKernelGGL(scan_kernel, dim3(GWG), dim3(256),
                           0, stream, zxf, rker, bias, out, hbuf8, cst, t0, t0 + tc);
    }
}